// Round 10
// baseline (3411.798 us; speedup 1.0000x reference)
//
#include <hip/hip_runtime.h>
#include <math.h>

#define HDIM 128
#define NSTEP 606
#define NW 8                    // waves per block
#define DSTR 129                // dpl row stride (floats)
#define ASTR 192                // activation floats per wave: [48 feats][4 px]

// dynamic-LDS carve (float indices)
#define O_DPL   0                           // 122*129 = 15738
#define O_WB    15740                       // 5 layers * 64 lanes * 36
#define O_WB6   (O_WB + 5*64*36)            // 64 lanes * 24 ([3][8] zero-padded)
#define O_T0    (O_WB6 + 64*24)             // NW*ASTR
#define O_TA    (O_T0 + NW*ASTR)            // NW*ASTR
#define O_HIST  (O_TA + NW*ASTR)            // 256 u32
#define O_WRED  (O_HIST + 256)              // NW
#define DYN_FLOATS (O_WRED + NW)
#define DYN_BYTES  (DYN_FLOATS * 4)         // ~128.5 KB

typedef float v2f __attribute__((ext_vector_type(2)));
typedef float v4f __attribute__((ext_vector_type(4)));

__device__ __forceinline__ void pk_fma(v2f& acc, v2f a, v2f b) {
  asm("v_pk_fma_f32 %0, %1, %2, %0" : "+v"(acc) : "v"(a), "v"(b));
}
__device__ __forceinline__ v2f vlo(v4f v) { return __builtin_shufflevector(v, v, 0, 1); }
__device__ __forceinline__ v2f vhi(v4f v) { return __builtin_shufflevector(v, v, 2, 3); }
__device__ __forceinline__ float lrelu(float z) { return (z >= 0.f) ? z : 0.01f * z; }

template <int CTRL>
__device__ __forceinline__ float dpp_qp(float v) {
  return __int_as_float(__builtin_amdgcn_mov_dpp(__float_as_int(v), CTRL, 0xf, 0xf, true));
}
__device__ __forceinline__ float quad_red(float v) {
  v += dpp_qp<0xB1>(v);   // quad_perm xor 1
  v += dpp_qp<0x4E>(v);   // quad_perm xor 2
  return v;
}
__device__ __forceinline__ float sel4f(float a0, float a1, float a2, float a3, int lane) {
  float m01 = (lane & 1) ? a1 : a0;
  float m23 = (lane & 1) ? a3 : a2;
  return (lane & 2) ? m23 : m01;
}
__device__ __forceinline__ int sel4i(int a0, int a1, int a2, int a3, int lane) {
  int m01 = (lane & 1) ? a1 : a0;
  int m23 = (lane & 1) ? a3 : a2;
  return (lane & 2) ? m23 : m01;
}

// One 48-in / 3-rows-per-lane layer: quad k-split, pk_fma, DPP quad-reduce.
template <bool RES>
__device__ __forceinline__ void mlp_layer48(
    const float* __restrict__ wb, const float* __restrict__ src,
    float* __restrict__ dst, const float* __restrict__ res,
    float b0, float b1, float b2, int q, int f0, int f1, int f2, bool wr)
{
  v2f a010 = {0,0}, a230 = {0,0}, a011 = {0,0}, a231 = {0,0}, a012 = {0,0}, a232 = {0,0};
  #pragma unroll
  for (int ic = 0; ic < 3; ++ic) {
    const v4f w0 = *(const v4f*)(wb + 4 * ic);
    const v4f w1 = *(const v4f*)(wb + 12 + 4 * ic);
    const v4f w2 = *(const v4f*)(wb + 24 + 4 * ic);
    #pragma unroll
    for (int kk = 0; kk < 4; ++kk) {
      const v4f tv = *(const v4f*)(src + 4 * (12 * q + 4 * ic + kk));
      const v2f t01 = vlo(tv), t23 = vhi(tv);
      const v2f s0 = {w0[kk], w0[kk]};
      const v2f s1 = {w1[kk], w1[kk]};
      const v2f s2 = {w2[kk], w2[kk]};
      pk_fma(a010, s0, t01); pk_fma(a230, s0, t23);
      pk_fma(a011, s1, t01); pk_fma(a231, s1, t23);
      pk_fma(a012, s2, t01); pk_fma(a232, s2, t23);
    }
  }
  {
    const float r0 = quad_red(a010.x), r1 = quad_red(a010.y);
    const float r2 = quad_red(a230.x), r3 = quad_red(a230.y);
    float v = lrelu(sel4f(r0, r1, r2, r3, q) + b0);
    if (RES) v += res[4 * f0 + q];
    if (wr) dst[4 * f0 + q] = v;
  }
  {
    const float r0 = quad_red(a011.x), r1 = quad_red(a011.y);
    const float r2 = quad_red(a231.x), r3 = quad_red(a231.y);
    float v = lrelu(sel4f(r0, r1, r2, r3, q) + b1);
    if (RES) v += res[4 * f1 + q];
    if (wr) dst[4 * f1 + q] = v;
  }
  {
    const float r0 = quad_red(a012.x), r1 = quad_red(a012.y);
    const float r2 = quad_red(a232.x), r3 = quad_red(a232.y);
    float v = lrelu(sel4f(r0, r1, r2, r3, q) + b2);
    if (RES) v += res[4 * f2 + q];
    if (wr) dst[4 * f2 + q] = v;
  }
}

__global__ __launch_bounds__(512)
void codec_main_kernel(const float* __restrict__ x,
    const float* __restrict__ W1, const float* __restrict__ b1,
    const float* __restrict__ W2, const float* __restrict__ b2,
    const float* __restrict__ W3, const float* __restrict__ b3,
    const float* __restrict__ W4, const float* __restrict__ b4,
    const float* __restrict__ W5, const float* __restrict__ b5,
    const float* __restrict__ W6, const float* __restrict__ b6,
    const float* __restrict__ W7, const float* __restrict__ b7,
    unsigned* __restrict__ g_hist, float* __restrict__ g_sumsq)
{
  extern __shared__ float dyn[];
  float* dpl = dyn + O_DPL;
  unsigned* hist = (unsigned*)(dyn + O_HIST);
  float* wred = dyn + O_WRED;

  const int tid = threadIdx.x, wid = tid >> 6, lane = tid & 63;
  const int plane = blockIdx.x;
  const float* xp = x + (size_t)plane * (HDIM * HDIM);
  float* t0b = dyn + O_T0 + wid * ASTR;     // [f][4px]
  float* tab = dyn + O_TA + wid * ASTR;

  // ---- pack per-lane blobs (L1-5): blob[(L*64+lane)*36 + rr*12 + kk] ----
  for (int j = tid; j < 5 * 64; j += 512) {
    const int L = j >> 6, l = j & 63;
    const int plt = l >> 2, pq = l & 3;
    float* dst = dyn + O_WB + j * 36;
    const float* W = (L == 0) ? W1 : (L == 1) ? W2 : (L == 2) ? W3 : (L == 3) ? W4 : W5;
    for (int rr = 0; rr < 3; ++rr) {
      const int row = (L < 4) ? (plt + 16 * rr) : ((plt & 7) + 8 * rr);
      for (int kk = 0; kk < 12; ++kk)
        dst[rr * 12 + kk] = W[row * 48 + 12 * pq + kk];
    }
  }
  // L6 blobs: [3 rows][8 (6 real + 2 zero)] per lane
  for (int j = tid; j < 64; j += 512) {
    const int lt6 = (j >> 2) & 3, q6 = j & 3;
    float* dst = dyn + O_WB6 + j * 24;
    for (int rr = 0; rr < 3; ++rr)
      for (int i = 0; i < 8; ++i)
        dst[rr * 8 + i] = (i < 6) ? W6[(lt6 + 4 * rr) * 24 + 6 * q6 + i] : 0.f;
  }
  for (int i = tid; i < 122 * DSTR; i += 512) dpl[i] = 0.f;
  for (int i = tid; i < NW * ASTR; i += 512) { dyn[O_T0 + i] = 0.f; dyn[O_TA + i] = 0.f; }
  if (tid < 256) hist[tid] = 0u;
  if (tid < NW) wred[tid] = 0.f;

  // ---- per-lane constants ----
  const int lt = lane >> 2, q = lane & 3;
  const int lt5 = lt & 7, lt6 = lt & 3;
  float b14[4][3];
  {
    const float* Bs[4] = {b1, b2, b3, b4};
    #pragma unroll
    for (int L = 0; L < 4; ++L)
      #pragma unroll
      for (int rr = 0; rr < 3; ++rr) b14[L][rr] = Bs[L][lt + 16 * rr];
  }
  float b5r[3], b6r[3], w7r[3];
  #pragma unroll
  for (int rr = 0; rr < 3; ++rr) {
    b5r[rr] = b5[lt5 + 8 * rr];
    b6r[rr] = b6[lt6 + 4 * rr];
    w7r[rr] = W7[lt6 + 4 * rr];
  }
  const float B7v = b7[0];
  const float* wbl = dyn + O_WB + lane * 36;
  const float* wb6 = dyn + O_WB6 + lane * 24;

  // ---- per-lane gather geometry ----
  const bool isx = (lane < 24);
  const bool isd = (lane >= 24 && lane < 48);
  int xro = 0, xco = 0, dro = 0, dco = 0;
  if (isx) { xro = (lane < 21) ? lane / 7 : 3; xco = (lane < 21) ? lane % 7 : (lane - 21); }
  if (isd) { const int g = lane - 24; dro = (g < 21) ? g / 7 - 3 : 0; dco = (g < 21) ? g % 7 : g - 21; }

  __syncthreads();

  float xpre[4] = {0.f, 0.f, 0.f, 0.f};
  float xcp = 0.f;                          // lane<4: center x of px=lane (for step T)
  float sumsq = 0.f;
  #pragma unroll
  for (int p = 0; p < 4; ++p) {
    const int r = (wid & 7) + 8 * p, j = 0 - 4 * r;
    if (isx && j >= 0 && r <= 121) xpre[p] = xp[(r + xro) * HDIM + (j + xco)];
  }
  if (lane < 4 && ((wid & 7) + 8 * lane) == 0) xcp = xp[3 * HDIM + 3];

  for (int T = 0; T < NSTEP; ++T) {
    const int r_lo = (T > 121) ? ((T - 118) >> 2) : 0;
    const int rbase = r_lo + ((wid - r_lo) & 7);

    int rs[4], js[4];
    bool act[4];
    #pragma unroll
    for (int p = 0; p < 4; ++p) {
      rs[p] = rbase + 8 * p;
      js[p] = T - 4 * rs[p];
      act[p] = (js[p] >= 0) && (rs[p] <= 121);
    }

    // ---- gather t0 [f][4px] (uses previous prefetch) ----
    if (act[0]) {
      float g0 = 0.f, g1 = 0.f, g2 = 0.f, g3 = 0.f;
      #pragma unroll
      for (int p = 0; p < 4; ++p) {
        float v = 0.f;
        if (act[p]) {
          if (isx) v = xpre[p];
          else if (isd) {
            const int drow = rs[p] + dro, dcol = js[p] + dco;
            v = (drow >= 0) ? dpl[drow * DSTR + dcol] : 0.f;
          }
        }
        if (p == 0) g0 = v; else if (p == 1) g1 = v; else if (p == 2) g2 = v; else g3 = v;
      }
      if (lane < 48) {
        v4f gv = {g0, g1, g2, g3};
        *(v4f*)(t0b + 4 * lane) = gv;
      }
    }

    // ---- unconditional prefetch for T+1 (x neighbors + center) ----
    float xcn = 0.f;
    {
      const int Tn = T + 1;
      const int r_lo_n = (Tn > 121) ? ((Tn - 118) >> 2) : 0;
      const int rbase_n = r_lo_n + ((wid - r_lo_n) & 7);
      #pragma unroll
      for (int p = 0; p < 4; ++p) {
        const int rn = rbase_n + 8 * p, jn = Tn - 4 * rn;
        if (isx && jn >= 0 && rn <= 121) xpre[p] = xp[(rn + xro) * HDIM + (jn + xco)];
      }
      if (lane < 4) {
        const int rn = rbase_n + 8 * lane, jn = Tn - 4 * rn;
        if (jn >= 0 && rn <= 121) xcn = xp[(rn + 3) * HDIM + (jn + 3)];
      }
    }

    if (act[0]) {
      // ---- L1-4 (+res on L4), L5 ----
      mlp_layer48<false>(wbl + 0 * 2304, t0b, tab, t0b, b14[0][0], b14[0][1], b14[0][2],
                         q, lt, lt + 16, lt + 32, true);
      mlp_layer48<false>(wbl + 1 * 2304, tab, tab, t0b, b14[1][0], b14[1][1], b14[1][2],
                         q, lt, lt + 16, lt + 32, true);
      mlp_layer48<false>(wbl + 2 * 2304, tab, tab, t0b, b14[2][0], b14[2][1], b14[2][2],
                         q, lt, lt + 16, lt + 32, true);
      mlp_layer48<true >(wbl + 3 * 2304, tab, tab, t0b, b14[3][0], b14[3][1], b14[3][2],
                         q, lt, lt + 16, lt + 32, true);
      mlp_layer48<false>(wbl + 4 * 2304, tab, tab, t0b, b5r[0], b5r[1], b5r[2],
                         q, lt5, lt5 + 8, lt5 + 16, lt < 8);

      // ---- L6 (12 rows, k = 6q+i) + L7 ----
      {
        v2f c010 = {0,0}, c230 = {0,0}, c011 = {0,0}, c231 = {0,0}, c012 = {0,0}, c232 = {0,0};
        const v4f wa0 = *(const v4f*)(wb6 + 0);
        const v2f wv0 = *(const v2f*)(wb6 + 4);
        const v4f wa1 = *(const v4f*)(wb6 + 8);
        const v2f wv1 = *(const v2f*)(wb6 + 12);
        const v4f wa2 = *(const v4f*)(wb6 + 16);
        const v2f wv2 = *(const v2f*)(wb6 + 20);
        #pragma unroll
        for (int i = 0; i < 6; ++i) {
          const v4f tv = *(const v4f*)(tab + 4 * (6 * q + i));
          const v2f t01 = vlo(tv), t23 = vhi(tv);
          const float c0 = (i < 4) ? wa0[i] : wv0[i - 4];
          const float c1 = (i < 4) ? wa1[i] : wv1[i - 4];
          const float c2 = (i < 4) ? wa2[i] : wv2[i - 4];
          const v2f s0 = {c0, c0}, s1 = {c1, c1}, s2 = {c2, c2};
          pk_fma(c010, s0, t01); pk_fma(c230, s0, t23);
          pk_fma(c011, s1, t01); pk_fma(c231, s1, t23);
          pk_fma(c012, s2, t01); pk_fma(c232, s2, t23);
        }
        float S0 = 0.f, S1 = 0.f, S2 = 0.f, S3 = 0.f;
        {
          const float h0 = lrelu(quad_red(c010.x) + b6r[0]);
          const float h1 = lrelu(quad_red(c010.y) + b6r[0]);
          const float h2 = lrelu(quad_red(c230.x) + b6r[0]);
          const float h3 = lrelu(quad_red(c230.y) + b6r[0]);
          S0 += w7r[0] * h0; S1 += w7r[0] * h1; S2 += w7r[0] * h2; S3 += w7r[0] * h3;
        }
        {
          const float h0 = lrelu(quad_red(c011.x) + b6r[1]);
          const float h1 = lrelu(quad_red(c011.y) + b6r[1]);
          const float h2 = lrelu(quad_red(c231.x) + b6r[1]);
          const float h3 = lrelu(quad_red(c231.y) + b6r[1]);
          S0 += w7r[1] * h0; S1 += w7r[1] * h1; S2 += w7r[1] * h2; S3 += w7r[1] * h3;
        }
        {
          const float h0 = lrelu(quad_red(c012.x) + b6r[2]);
          const float h1 = lrelu(quad_red(c012.y) + b6r[2]);
          const float h2 = lrelu(quad_red(c232.x) + b6r[2]);
          const float h3 = lrelu(quad_red(c232.y) + b6r[2]);
          S0 += w7r[2] * h0; S1 += w7r[2] * h1; S2 += w7r[2] * h2; S3 += w7r[2] * h3;
        }
        // sum over lt&3 groups (lane bits 2,3); bits 4,5 are duplicates
        S0 += __shfl_xor(S0, 4); S0 += __shfl_xor(S0, 8);
        S1 += __shfl_xor(S1, 4); S1 += __shfl_xor(S1, 8);
        S2 += __shfl_xor(S2, 4); S2 += __shfl_xor(S2, 8);
        S3 += __shfl_xor(S3, 4); S3 += __shfl_xor(S3, 8);

        if (lane < 4) {
          const bool ap = sel4i((int)act[0], (int)act[1], (int)act[2], (int)act[3], lane);
          if (ap) {
            const float pv = sel4f(S0, S1, S2, S3, lane) + B7v;
            const int rp = sel4i(rs[0], rs[1], rs[2], rs[3], lane);
            const int jp = sel4i(js[0], js[1], js[2], js[3], lane);
            const float pred = fminf(1.f, fmaxf(-1.f, pv));
            const float delta = xcp - pred;
            dpl[rp * DSTR + jp + 3] = delta;
            sumsq += delta * delta;
            if (delta <= 1.0f) {
              int bin = (int)((delta + 1.0f) * 128.0f);
              bin = bin > 255 ? 255 : (bin < 0 ? 0 : bin);
              atomicAdd(&hist[bin], 1u);
            }
          }
        }
      }
    }
    xcp = xcn;
    __syncthreads();
  }

  // ---- stats flush ----
  {
    float v = sumsq;
    #pragma unroll
    for (int off = 32; off; off >>= 1) v += __shfl_down(v, off);
    if (lane == 0) wred[wid] = v;
  }
  __syncthreads();
  if (tid == 0) {
    float s = 0.f;
    #pragma unroll
    for (int w = 0; w < NW; ++w) s += wred[w];
    g_sumsq[plane] = s;
  }
  if (tid < 256) {
    const unsigned c = hist[tid];
    if (c) atomicAdd(&g_hist[tid], c);
  }
}

__global__ void codec_init_kernel(unsigned* g_hist, float* g_sumsq) {
  const int t = threadIdx.x;
  if (t < 256) g_hist[t] = 0u;
  if (t < 24)  g_sumsq[t] = 0.f;
}

__global__ void codec_final_kernel(const unsigned* __restrict__ g_hist,
                                   const float* __restrict__ g_sumsq,
                                   float* __restrict__ out)
{
  __shared__ float sred[256];
  const int t = threadIdx.x;
  sred[t] = (t < 24) ? g_sumsq[t] : 0.f;
  __syncthreads();
  for (int off = 128; off; off >>= 1) {
    if (t < off) sred[t] += sred[t + off];
    __syncthreads();
  }
  const float loss = sqrtf(sred[0] / 387072.f);   // 8*3*126*128
  __syncthreads();

  const unsigned c = g_hist[t] + (t == 128 ? 2928u : 0u);  // bottom zero-row
  float ent = 0.f;
  if (c) {
    const float pr = (float)c / 360144.0f;        // 24*123*122
    ent = -pr * log2f(pr);
  }
  sred[t] = ent;
  __syncthreads();
  for (int off = 128; off; off >>= 1) {
    if (t < off) sred[t] += sred[t + off];
    __syncthreads();
  }
  if (t == 0) { out[0] = loss; out[1] = sred[0] * 0.125f; }
}

extern "C" void kernel_launch(void* const* d_in, const int* in_sizes, int n_in,
                              void* d_out, int out_size, void* d_ws, size_t ws_size,
                              hipStream_t stream) {
  const float* x  = (const float*)d_in[0];
  const float* W1 = (const float*)d_in[1];  const float* b1 = (const float*)d_in[2];
  const float* W2 = (const float*)d_in[3];  const float* b2 = (const float*)d_in[4];
  const float* W3 = (const float*)d_in[5];  const float* b3 = (const float*)d_in[6];
  const float* W4 = (const float*)d_in[7];  const float* b4 = (const float*)d_in[8];
  const float* W5 = (const float*)d_in[9];  const float* b5 = (const float*)d_in[10];
  const float* W6 = (const float*)d_in[11]; const float* b6 = (const float*)d_in[12];
  const float* W7 = (const float*)d_in[13]; const float* b7 = (const float*)d_in[14];

  unsigned* g_hist = (unsigned*)d_ws;           // 256 u32
  float* g_sumsq = (float*)d_ws + 256;          // 24 f32

  (void)hipFuncSetAttribute((const void*)codec_main_kernel,
                            hipFuncAttributeMaxDynamicSharedMemorySize, DYN_BYTES);

  codec_init_kernel<<<1, 256, 0, stream>>>(g_hist, g_sumsq);
  codec_main_kernel<<<24, 512, DYN_BYTES, stream>>>(x, W1, b1, W2, b2, W3, b3,
                                                    W4, b4, W5, b5, W6, b6, W7, b7,
                                                    g_hist, g_sumsq);
  codec_final_kernel<<<1, 256, 0, stream>>>(g_hist, g_sumsq, (float*)d_out);
}

// Round 11
// 2971.935 us; speedup vs baseline: 1.1480x; 1.1480x over previous
//
#include <hip/hip_runtime.h>
#include <math.h>

#define HDIM 128
#define NSTEP 606
#define NW 16                   // waves per block (1024 threads)
#define DSTR 129                // dpl row stride (floats)
#define PSTR 52                 // per-pixel activation stride (floats)
#define AWAVE (2 * PSTR)        // activation floats per wave per buffer

// dynamic-LDS carve (float indices)
#define O_DPL   0                           // 122*129 = 15738
#define O_WB14  15740                       // 4L * 16lt * 2h * 72 = 9216
#define O_WB5   (O_WB14 + 9216)             // 12*2*48 = 1152
#define O_WB6   (O_WB5 + 1152)              // 12*2*12 = 288
#define O_T0    (O_WB6 + 288)               // NW*AWAVE = 1664
#define O_TA    (O_T0 + NW*AWAVE)           // 1664
#define O_HIST  (O_TA + NW*AWAVE)           // 256
#define O_WRED  (O_HIST + 256)              // NW
#define DYN_FLOATS (O_WRED + NW)
#define DYN_BYTES  (DYN_FLOATS * 4)         // ~117.2 KB

typedef float v2f __attribute__((ext_vector_type(2)));
typedef float v4f __attribute__((ext_vector_type(4)));

__device__ __forceinline__ void pk_fma(v2f& acc, v2f a, v2f b) {
  asm("v_pk_fma_f32 %0, %1, %2, %0" : "+v"(acc) : "v"(a), "v"(b));
}
__device__ __forceinline__ v2f vlo(v4f v) { return __builtin_shufflevector(v, v, 0, 1); }
__device__ __forceinline__ v2f vhi(v4f v) { return __builtin_shufflevector(v, v, 2, 3); }
__device__ __forceinline__ float lrelu(float z) { return (z >= 0.f) ? z : 0.01f * z; }

template <int CTRL>
__device__ __forceinline__ float dpp_qp(float v) {
  return __int_as_float(__builtin_amdgcn_mov_dpp(__float_as_int(v), CTRL, 0xf, 0xf, true));
}
// add partner value across the k-half split (lane ^ 2)
__device__ __forceinline__ float khalf_red(float v) {
  return v + dpp_qp<0x4E>(v);   // quad_perm [2,3,0,1]
}

__global__ __launch_bounds__(1024)
void codec_main_kernel(const float* __restrict__ x,
    const float* __restrict__ W1, const float* __restrict__ b1,
    const float* __restrict__ W2, const float* __restrict__ b2,
    const float* __restrict__ W3, const float* __restrict__ b3,
    const float* __restrict__ W4, const float* __restrict__ b4,
    const float* __restrict__ W5, const float* __restrict__ b5,
    const float* __restrict__ W6, const float* __restrict__ b6,
    const float* __restrict__ W7, const float* __restrict__ b7,
    unsigned* __restrict__ g_hist, float* __restrict__ g_sumsq)
{
  extern __shared__ float dyn[];
  float* dpl = dyn + O_DPL;
  unsigned* hist = (unsigned*)(dyn + O_HIST);
  float* wred = dyn + O_WRED;

  const int tid = threadIdx.x, wid = tid >> 6, lane = tid & 63;
  const int plane = blockIdx.x;
  const float* xp = x + (size_t)plane * (HDIM * HDIM);
  float* t0b = dyn + O_T0 + wid * AWAVE;    // [2px][PSTR]
  float* tab = dyn + O_TA + wid * AWAVE;

  // ---- pack weight blobs (shared per (L,lt,h)) ----
  {
    const float* Ws[4] = {W1, W2, W3, W4};
    for (int i = tid; i < 9216; i += 1024) {
      const int slot = i / 72, f = i % 72;
      const int L = slot >> 5, lt = (slot & 31) >> 1, h = slot & 1;
      const int rr = f / 24, kk = f % 24;
      dyn[O_WB14 + i] = Ws[L][(lt + 16 * rr) * 48 + h * 24 + kk];
    }
  }
  for (int i = tid; i < 1152; i += 1024) {
    const int slot = i / 48, f = i % 48;
    const int lt = slot >> 1, h = slot & 1;
    const int rr = f / 24, kk = f % 24;
    dyn[O_WB5 + i] = W5[(lt + 12 * rr) * 48 + h * 24 + kk];
  }
  for (int i = tid; i < 288; i += 1024) {
    const int slot = i / 12, f = i % 12;
    const int lt = slot >> 1, h = slot & 1;
    dyn[O_WB6 + i] = W6[lt * 24 + h * 12 + f];
  }
  for (int i = tid; i < 122 * DSTR; i += 1024) dpl[i] = 0.f;
  for (int i = tid; i < NW * AWAVE; i += 1024) { dyn[O_T0 + i] = 0.f; dyn[O_TA + i] = 0.f; }
  if (tid < 256) hist[tid] = 0u;
  if (tid < NW) wred[tid] = 0.f;

  // ---- per-lane constants ----
  const int lt = lane >> 2, q = lane & 3;
  const int p = q & 1, h = q >> 1;          // pixel slot, k-half
  const int lt12 = (lt < 12) ? lt : 0;
  float b14v[4][3];
  {
    const float* Bs[4] = {b1, b2, b3, b4};
    #pragma unroll
    for (int L = 0; L < 4; ++L)
      #pragma unroll
      for (int rr = 0; rr < 3; ++rr) b14v[L][rr] = Bs[L][lt + 16 * rr];
  }
  const float b5r0 = b5[lt12], b5r1 = b5[lt12 + 12];
  const float b6v = b6[lt12];
  const float w7r = (lt < 12 && h == 0) ? W7[lt] : 0.f;   // h-mask avoids double count
  const float B7v = b7[0];
  const float* wbl = dyn + O_WB14 + (lt * 2 + h) * 72;    // + L*2304
  const float* wb5 = dyn + O_WB5 + (lt12 * 2 + h) * 48;
  const float* wb6 = dyn + O_WB6 + (lt12 * 2 + h) * 12;

  // ---- gather geometry (lane = feature index 0..47) ----
  const bool isx = (lane < 24);
  const bool isd = (lane >= 24 && lane < 48);
  int xro = 0, xco = 0, dro = 0, dco = 0;
  if (isx) { xro = (lane < 21) ? lane / 7 : 3; xco = (lane < 21) ? lane % 7 : (lane - 21); }
  if (isd) { const int g = lane - 24; dro = (g < 21) ? g / 7 - 3 : 0; dco = (g < 21) ? g % 7 : g - 21; }

  __syncthreads();

  float xpre[2] = {0.f, 0.f};
  float xcp = 0.f;                          // lane<2: center x for px=lane at step T
  float sumsq = 0.f;
  #pragma unroll
  for (int pp = 0; pp < 2; ++pp) {
    const int r = wid + 16 * pp, j = 0 - 4 * r;
    if (isx && j >= 0 && r <= 121) xpre[pp] = xp[(r + xro) * HDIM + (j + xco)];
  }
  if (lane < 2 && (wid + 16 * lane) == 0) xcp = xp[3 * HDIM + 3];

  for (int T = 0; T < NSTEP; ++T) {
    const int r_lo = (T > 121) ? ((T - 118) >> 2) : 0;
    const int rbase = r_lo + ((wid - r_lo) & 15);

    int rs[2], js[2];
    bool act[2];
    #pragma unroll
    for (int pp = 0; pp < 2; ++pp) {
      rs[pp] = rbase + 16 * pp;
      js[pp] = T - 4 * rs[pp];
      act[pp] = (js[pp] >= 0) && (rs[pp] <= 121);
    }

    // ---- gather t0 [px][f] ----
    if (act[0]) {
      #pragma unroll
      for (int pp = 0; pp < 2; ++pp) {
        if (act[pp]) {
          float v = 0.f;
          if (isx) v = xpre[pp];
          else if (isd) {
            const int drow = rs[pp] + dro, dcol = js[pp] + dco;
            v = (drow >= 0) ? dpl[drow * DSTR + dcol] : 0.f;
          }
          if (lane < 48) t0b[pp * PSTR + lane] = v;
        }
      }
    }

    // ---- unconditional prefetch for T+1 ----
    float xcn = 0.f;
    {
      const int Tn = T + 1;
      const int r_lo_n = (Tn > 121) ? ((Tn - 118) >> 2) : 0;
      const int rbase_n = r_lo_n + ((wid - r_lo_n) & 15);
      #pragma unroll
      for (int pp = 0; pp < 2; ++pp) {
        const int rn = rbase_n + 16 * pp, jn = Tn - 4 * rn;
        if (isx && jn >= 0 && rn <= 121) xpre[pp] = xp[(rn + xro) * HDIM + (jn + xco)];
      }
      if (lane < 2) {
        const int rn = rbase_n + 16 * lane, jn = Tn - 4 * rn;
        if (jn >= 0 && rn <= 121) xcn = xp[(rn + 3) * HDIM + (jn + 3)];
      }
    }

    if (act[0]) {
      const int ab = p * PSTR;              // this lane's pixel base

      // ---- L1-4: 3 rows/lane, k-half split, khalf_red ----
      #pragma unroll
      for (int L = 0; L < 4; ++L) {
        const float* src = ((L == 0) ? t0b : tab) + ab + h * 24;
        const float* wb = wbl + L * 2304;
        v2f a0 = {0,0}, a1 = {0,0}, a2 = {0,0};
        #pragma unroll
        for (int i = 0; i < 6; ++i) {
          const v4f tv = *(const v4f*)(src + 4 * i);
          const v4f w0 = *(const v4f*)(wb + 4 * i);
          const v4f w1 = *(const v4f*)(wb + 24 + 4 * i);
          const v4f w2 = *(const v4f*)(wb + 48 + 4 * i);
          pk_fma(a0, vlo(w0), vlo(tv)); pk_fma(a0, vhi(w0), vhi(tv));
          pk_fma(a1, vlo(w1), vlo(tv)); pk_fma(a1, vhi(w1), vhi(tv));
          pk_fma(a2, vlo(w2), vlo(tv)); pk_fma(a2, vhi(w2), vhi(tv));
        }
        float r0 = khalf_red(a0.x + a0.y);
        float r1 = khalf_red(a1.x + a1.y);
        float r2 = khalf_red(a2.x + a2.y);
        float o0 = lrelu(r0 + b14v[L][0]);
        float o1 = lrelu(r1 + b14v[L][1]);
        float o2 = lrelu(r2 + b14v[L][2]);
        if (L == 3) {
          o0 += t0b[ab + lt];
          o1 += t0b[ab + lt + 16];
          o2 += t0b[ab + lt + 32];
        }
        if (h == 0) {
          tab[ab + lt]      = o0;
          tab[ab + lt + 16] = o1;
          tab[ab + lt + 32] = o2;
        }
      }

      // ---- L5: 48->24, rows lt12, lt12+12 ----
      {
        const float* src = tab + ab + h * 24;
        v2f a0 = {0,0}, a1 = {0,0};
        #pragma unroll
        for (int i = 0; i < 6; ++i) {
          const v4f tv = *(const v4f*)(src + 4 * i);
          const v4f w0 = *(const v4f*)(wb5 + 4 * i);
          const v4f w1 = *(const v4f*)(wb5 + 24 + 4 * i);
          pk_fma(a0, vlo(w0), vlo(tv)); pk_fma(a0, vhi(w0), vhi(tv));
          pk_fma(a1, vlo(w1), vlo(tv)); pk_fma(a1, vhi(w1), vhi(tv));
        }
        const float r0 = khalf_red(a0.x + a0.y);
        const float r1 = khalf_red(a1.x + a1.y);
        const float o0 = lrelu(r0 + b5r0);
        const float o1 = lrelu(r1 + b5r1);
        if (h == 0 && lt < 12) {
          t0b[ab + lt12]      = o0;
          t0b[ab + lt12 + 12] = o1;
        }
      }

      // ---- L6: 24->12 (row lt12) + L7 ----
      {
        const float* src = t0b + ab + h * 12;
        v2f a = {0,0};
        #pragma unroll
        for (int i = 0; i < 3; ++i) {
          const v4f tv = *(const v4f*)(src + 4 * i);
          const v4f wv = *(const v4f*)(wb6 + 4 * i);
          pk_fma(a, vlo(wv), vlo(tv)); pk_fma(a, vhi(wv), vhi(tv));
        }
        const float r = khalf_red(a.x + a.y);
        const float h6 = lrelu(r + b6v);
        float s = w7r * h6;                 // 0 for lt>=12 or h==1
        s += __shfl_xor(s, 4);
        s += __shfl_xor(s, 8);
        s += __shfl_xor(s, 16);
        s += __shfl_xor(s, 32);

        if (lane < 2) {
          const bool ap = (lane == 0) ? act[0] : act[1];
          if (ap) {
            const int rp = (lane == 0) ? rs[0] : rs[1];
            const int jp = (lane == 0) ? js[0] : js[1];
            const float pred = fminf(1.f, fmaxf(-1.f, s + B7v));
            const float delta = xcp - pred;
            dpl[rp * DSTR + jp + 3] = delta;
            sumsq += delta * delta;
            if (delta <= 1.0f) {
              int bin = (int)((delta + 1.0f) * 128.0f);
              bin = bin > 255 ? 255 : (bin < 0 ? 0 : bin);
              atomicAdd(&hist[bin], 1u);
            }
          }
        }
      }
    }
    xcp = xcn;
    __syncthreads();
  }

  // ---- stats flush ----
  {
    float v = sumsq;
    #pragma unroll
    for (int off = 32; off; off >>= 1) v += __shfl_down(v, off);
    if (lane == 0) wred[wid] = v;
  }
  __syncthreads();
  if (tid == 0) {
    float s = 0.f;
    #pragma unroll
    for (int w = 0; w < NW; ++w) s += wred[w];
    g_sumsq[plane] = s;
  }
  if (tid < 256) {
    const unsigned c = hist[tid];
    if (c) atomicAdd(&g_hist[tid], c);
  }
}

__global__ void codec_init_kernel(unsigned* g_hist, float* g_sumsq) {
  const int t = threadIdx.x;
  if (t < 256) g_hist[t] = 0u;
  if (t < 24)  g_sumsq[t] = 0.f;
}

__global__ void codec_final_kernel(const unsigned* __restrict__ g_hist,
                                   const float* __restrict__ g_sumsq,
                                   float* __restrict__ out)
{
  __shared__ float sred[256];
  const int t = threadIdx.x;
  sred[t] = (t < 24) ? g_sumsq[t] : 0.f;
  __syncthreads();
  for (int off = 128; off; off >>= 1) {
    if (t < off) sred[t] += sred[t + off];
    __syncthreads();
  }
  const float loss = sqrtf(sred[0] / 387072.f);   // 8*3*126*128
  __syncthreads();

  const unsigned c = g_hist[t] + (t == 128 ? 2928u : 0u);  // bottom zero-row
  float ent = 0.f;
  if (c) {
    const float pr = (float)c / 360144.0f;        // 24*123*122
    ent = -pr * log2f(pr);
  }
  sred[t] = ent;
  __syncthreads();
  for (int off = 128; off; off >>= 1) {
    if (t < off) sred[t] += sred[t + off];
    __syncthreads();
  }
  if (t == 0) { out[0] = loss; out[1] = sred[0] * 0.125f; }
}

extern "C" void kernel_launch(void* const* d_in, const int* in_sizes, int n_in,
                              void* d_out, int out_size, void* d_ws, size_t ws_size,
                              hipStream_t stream) {
  const float* x  = (const float*)d_in[0];
  const float* W1 = (const float*)d_in[1];  const float* b1 = (const float*)d_in[2];
  const float* W2 = (const float*)d_in[3];  const float* b2 = (const float*)d_in[4];
  const float* W3 = (const float*)d_in[5];  const float* b3 = (const float*)d_in[6];
  const float* W4 = (const float*)d_in[7];  const float* b4 = (const float*)d_in[8];
  const float* W5 = (const float*)d_in[9];  const float* b5 = (const float*)d_in[10];
  const float* W6 = (const float*)d_in[11]; const float* b6 = (const float*)d_in[12];
  const float* W7 = (const float*)d_in[13]; const float* b7 = (const float*)d_in[14];

  unsigned* g_hist = (unsigned*)d_ws;           // 256 u32
  float* g_sumsq = (float*)d_ws + 256;          // 24 f32

  (void)hipFuncSetAttribute((const void*)codec_main_kernel,
                            hipFuncAttributeMaxDynamicSharedMemorySize, DYN_BYTES);

  codec_init_kernel<<<1, 256, 0, stream>>>(g_hist, g_sumsq);
  codec_main_kernel<<<24, 1024, DYN_BYTES, stream>>>(x, W1, b1, W2, b2, W3, b3,
                                                     W4, b4, W5, b5, W6, b6, W7, b7,
                                                     g_hist, g_sumsq);
  codec_final_kernel<<<1, 256, 0, stream>>>(g_hist, g_sumsq, (float*)d_out);
}